// Round 14
// baseline (288.336 us; speedup 1.0000x reference)
//
#include <hip/hip_runtime.h>
#include <hip/hip_bf16.h>

typedef float f32x4 __attribute__((ext_vector_type(4)));
typedef __bf16 bf16x8 __attribute__((ext_vector_type(8)));
typedef __bf16 bf16x4 __attribute__((ext_vector_type(4)));
typedef unsigned short u16x8 __attribute__((ext_vector_type(8)));
typedef unsigned short u16x4 __attribute__((ext_vector_type(4)));

#define QSCALE 0.180336881f  /* 0.125 * log2(e): folds attn scale + exp2 domain into Q */

__device__ __forceinline__ unsigned short f2bf(float f) {
  union { float f; unsigned int u; } v; v.f = f;
  return (unsigned short)((v.u + 0x7FFFu + ((v.u >> 16) & 1u)) >> 16);
}

__device__ __forceinline__ f32x4 mfma16(bf16x8 a, bf16x8 b, f32x4 c) {
  return __builtin_amdgcn_mfma_f32_16x16x32_bf16(a, b, c, 0, 0, 0);
}

__device__ __forceinline__ void gload16(const unsigned short* g, unsigned short* l) {
  __builtin_amdgcn_global_load_lds(
      (const __attribute__((address_space(1))) void*)g,
      (__attribute__((address_space(3))) void*)l, 16, 0, 0);
}

// ---------------- small utility kernels ----------------

__global__ void concat_bias_k(const float* __restrict__ qb, const float* __restrict__ kb,
                              const float* __restrict__ vb, float* __restrict__ out) {
  const int i = blockIdx.x * 256 + threadIdx.x;
  if (i >= 3072) return;
  const float* s = (i < 1024) ? qb : (i < 2048 ? kb : vb);
  out[i] = s[i & 1023] * (i < 1024 ? QSCALE : 1.0f);
}

// fp32 [R,C] -> bf16 [C,R]
__global__ void tcvt_k(const float* __restrict__ in, unsigned short* __restrict__ out,
                       int R, int C) {
  __shared__ float tile[32][33];
  const int x = blockIdx.x * 32 + threadIdx.x;
  const int y0 = blockIdx.y * 32;
#pragma unroll
  for (int i = 0; i < 32; i += 8)
    tile[threadIdx.y + i][threadIdx.x] = in[(size_t)(y0 + threadIdx.y + i) * C + x];
  __syncthreads();
  const int ox = y0 + threadIdx.x;
  const int oy0 = blockIdx.x * 32;
#pragma unroll
  for (int i = 0; i < 32; i += 8)
    out[(size_t)(oy0 + threadIdx.y + i) * R + ox] = f2bf(tile[threadIdx.x][threadIdx.y + i]);
}

__global__ void cvt_k(const float* __restrict__ in, unsigned short* __restrict__ out, int n) {
  const int i = (blockIdx.x * 256 + threadIdx.x) * 4;
  if (i >= n) return;
  const f32x4 v = *(const f32x4*)(in + i);
  u16x4 o;
#pragma unroll
  for (int k = 0; k < 4; ++k) o[k] = f2bf(v[k]);
  *(u16x4*)(out + i) = o;
}

// V-transpose: QKV[b][s][2048 + h*64 + d] -> VT[(b*16+h)][d][s]  (bf16)
__global__ void vtr_k(const unsigned short* __restrict__ QKV, unsigned short* __restrict__ VT) {
  __shared__ unsigned short tile[32][33];
  const int bh = blockIdx.z, b = bh >> 4, h = bh & 15;
  const int s0 = blockIdx.x * 32, d0 = blockIdx.y * 32;
  const unsigned short* src = QKV + (size_t)b * 2048 * 3072 + 2048 + h * 64;
#pragma unroll
  for (int i = 0; i < 32; i += 8)
    tile[threadIdx.y + i][threadIdx.x] = src[(size_t)(s0 + threadIdx.y + i) * 3072 + d0 + threadIdx.x];
  __syncthreads();
  unsigned short* dst = VT + (size_t)bh * 64 * 2048;
#pragma unroll
  for (int i = 0; i < 32; i += 8)
    dst[(size_t)(d0 + threadIdx.y + i) * 2048 + s0 + threadIdx.x] = tile[threadIdx.x][threadIdx.y + i];
}

// Wqkv^T[(m*1024 + h*64 + e)*1024 + d] = sum_r U_m[d,h,r] * V_m[h,r,e]  (Q part scaled)
__global__ __launch_bounds__(256) void wqkv_pre_k(
    const float* __restrict__ qU, const float* __restrict__ qV,
    const float* __restrict__ kU, const float* __restrict__ kV,
    const float* __restrict__ vU, const float* __restrict__ vV,
    unsigned short* __restrict__ WT) {
  __shared__ float Us[64][48];
  __shared__ float Vs[48][64];
  const int m = blockIdx.y >> 4, h = blockIdx.y & 15;
  const int d0 = blockIdx.x * 64;
  const float* U = (m == 0) ? qU : (m == 1 ? kU : vU);
  const float* V = (m == 0) ? qV : (m == 1 ? kV : vV);
  const float qs = (m == 0) ? QSCALE : 1.0f;
  const int t = threadIdx.x;
  for (int idx = t; idx < 64 * 48; idx += 256) {
    const int d = idx / 48, r = idx - d * 48;
    Us[d][r] = U[(size_t)(d0 + d) * 768 + h * 48 + r];
  }
  for (int idx = t; idx < 48 * 64; idx += 256) {
    const int r = idx >> 6, e = idx & 63;
    Vs[r][e] = V[(h * 48 + r) * 64 + e];
  }
  __syncthreads();
  const int e = t & 63, dg = t >> 6;
  for (int j = 0; j < 16; ++j) {
    const int d = dg * 16 + j;
    float s = 0.f;
#pragma unroll
    for (int r = 0; r < 48; ++r) s = fmaf(Us[d][r], Vs[r][e], s);
    WT[(size_t)(m * 1024 + h * 64 + e) * 1024 + d0 + d] = f2bf(s * qs);
  }
}

// LayerNorm over D=1024, fp32 in, bf16 out. One block per row.
__global__ __launch_bounds__(256) void ln_k(
    const float* __restrict__ in, const float* __restrict__ gw,
    const float* __restrict__ bw, unsigned short* __restrict__ out) {
  const int row = blockIdx.x, t = threadIdx.x;
  const f32x4 v = *(const f32x4*)(in + (size_t)row * 1024 + t * 4);
  float s = v[0] + v[1] + v[2] + v[3];
  float ss = v[0] * v[0] + v[1] * v[1] + v[2] * v[2] + v[3] * v[3];
#pragma unroll
  for (int off = 1; off < 64; off <<= 1) {
    s += __shfl_xor(s, off);
    ss += __shfl_xor(ss, off);
  }
  __shared__ float red[8];
  if ((t & 63) == 0) { red[(t >> 6) * 2] = s; red[(t >> 6) * 2 + 1] = ss; }
  __syncthreads();
  s = red[0] + red[2] + red[4] + red[6];
  ss = red[1] + red[3] + red[5] + red[7];
  const float mean = s * (1.0f / 1024.0f);
  const float rstd = rsqrtf(ss * (1.0f / 1024.0f) - mean * mean + 1e-5f);
  const f32x4 g4 = *(const f32x4*)(gw + t * 4);
  const f32x4 b4 = *(const f32x4*)(bw + t * 4);
  u16x4 o;
#pragma unroll
  for (int i = 0; i < 4; ++i) o[i] = f2bf((v[i] - mean) * rstd * g4[i] + b4[i]);
  *(u16x4*)(out + (size_t)row * 1024 + t * 4) = o;
}

// bijective XCD chunking (m157/m204)
__device__ __forceinline__ void xcd_swz(int& bx, int& by, int nx, int ny) {
  const int nwg = nx * ny;
  if ((nwg & 7) == 0) {
    const int d = by * nx + bx;
    const int k = (d & 7) * (nwg >> 3) + (d >> 3);
    bx = k % nx;
    by = k / nx;
  }
}

// ---------------- generic bf16 MFMA GEMM (2-buffer, occupancy-first) ----------------
// C[M,N] = A[M,K] @ Bt[N,K]^T. BM in {64,128}, BN in {64,128}. 256 threads =
// 4 waves (2x2), wave tile (BM/2)x(BN/2). Simple 2-buffer drain schedule —
// R10..R13 showed scheduling variants are neutral at these K-short shapes and
// blocks/CU is the only lever; LDS is kept at 2 buffers (16-32 KB) so 5-8
// blocks co-reside and hide each other's per-iteration latency. bf16 output
// goes through a wave-private LDS bounce in 2 passes (18 KB) for coalesced
// b128 stores.
template <int BM, int BN, int EPI, int OUTBF>
__global__ __launch_bounds__(256) void gemm_k(
    const unsigned short* __restrict__ A, const unsigned short* __restrict__ Bt,
    const float* __restrict__ bias, const float* __restrict__ resid,
    void* __restrict__ Cout, int M, int N, int K) {
  constexpr int MI = BM / 32;
  constexpr int FN = BN / 32;
  constexpr int ASZ = BM * 32, BSZ = BN * 32;
  constexpr int SM_KLOOP = 2 * (ASZ + BSZ);
  constexpr int SM_EPI = OUTBF ? 4 * 32 * 72 : 0;
  constexpr int SME = SM_KLOOP > SM_EPI ? SM_KLOOP : SM_EPI;
  __shared__ unsigned short smem[SME];
  unsigned short* As = smem;                  // [2][ASZ]
  unsigned short* Bs = smem + 2 * ASZ;        // [2][BSZ]
  int bxi = blockIdx.x, byi = blockIdx.y;
  xcd_swz(bxi, byi, gridDim.x, gridDim.y);
  const int t = threadIdx.x;
  const int lane = t & 63, wid = t >> 6;
  const int m0 = byi * BM, n0 = bxi * BN;
  const int wm = (wid >> 1) * (BM / 2), wn = (wid & 1) * (BN / 2);
  const int fr = lane & 15, fg = (lane >> 4) * 8;

  f32x4 acc[MI][FN];
#pragma unroll
  for (int i = 0; i < MI; ++i)
#pragma unroll
    for (int j = 0; j < FN; ++j) acc[i][j] = (f32x4){0.f, 0.f, 0.f, 0.f};

  const unsigned short* Ag0 = A + (size_t)(m0 + (t >> 2)) * K + (t & 3) * 8;
  const unsigned short* Ag1 = A + (size_t)(m0 + 64 + (t >> 2)) * K + (t & 3) * 8;
  const unsigned short* Bg0 = Bt + (size_t)(n0 + (t >> 2)) * K + (t & 3) * 8;
  const unsigned short* Bg1 = Bt + (size_t)(n0 + 64 + (t >> 2)) * K + (t & 3) * 8;
  const int l0 = t * 8;

#define GEMM_STAGE(buf, ke)                                               \
  {                                                                       \
    gload16(Ag0 + (ke), &As[(buf) * ASZ + l0]);                           \
    if (BM == 128) gload16(Ag1 + (ke), &As[(buf) * ASZ + l0 + 2048]);     \
    gload16(Bg0 + (ke), &Bs[(buf) * BSZ + l0]);                           \
    if (BN == 128) gload16(Bg1 + (ke), &Bs[(buf) * BSZ + l0 + 2048]);     \
  }

  const int nk = K >> 5;
  GEMM_STAGE(0, 0);

  for (int kt = 0; kt < nk; ++kt) {
    const int cur = kt & 1;
    __syncthreads();  // drains vmcnt: buf[cur] staged; prev reads of buf[cur^1] done
    if (kt + 1 < nk) GEMM_STAGE(cur ^ 1, (kt + 1) * 32);
    bf16x8 af[MI], bfr[FN];
#pragma unroll
    for (int i = 0; i < MI; ++i)
      af[i] = *(const bf16x8*)&As[cur * ASZ + (wm + i * 16 + fr) * 32 + fg];
#pragma unroll
    for (int j = 0; j < FN; ++j)
      bfr[j] = *(const bf16x8*)&Bs[cur * BSZ + (wn + j * 16 + fr) * 32 + fg];
#pragma unroll
    for (int i = 0; i < MI; ++i)
#pragma unroll
      for (int j = 0; j < FN; ++j) acc[i][j] = mfma16(af[i], bfr[j], acc[i][j]);
  }
#undef GEMM_STAGE

  if (OUTBF) {
    __syncthreads();  // all waves out of the K-loop before smem reuse
    unsigned short* eb = smem + wid * (32 * 72);  // wave-private [32][72] bf16
    unsigned short* Cg = (unsigned short*)Cout;
    constexpr int CH = (BN / 2) / 8;   // 16B chunks per output row
    constexpr int RPS = 64 / CH;       // rows covered per store sweep
    const int c2 = lane % CH, r2b = lane / CH;
#pragma unroll
    for (int hp = 0; hp < MI / 2; ++hp) {  // 32 output rows per pass
#pragma unroll
      for (int j = 0; j < FN; ++j) {
        const int colL = j * 16 + fr;                     // wave-local column
        const float bval = (EPI >= 1) ? bias[n0 + wn + colL] : 0.0f;
#pragma unroll
        for (int i2 = 0; i2 < 2; ++i2) {
#pragma unroll
          for (int r = 0; r < 4; ++r) {
            const int rl = i2 * 16 + ((lane >> 4) << 2) + r;
            float v = acc[hp * 2 + i2][j][r] + bval;
            if (EPI == 2) {  // gelu tanh-approx: v * sigmoid(2z)
              const float z = 0.7978845608028654f * (v + 0.044715f * v * v * v);
              v = v - v / (__expf(2.0f * z) + 1.0f);
            }
            eb[rl * 72 + colL] = f2bf(v);
          }
        }
      }
      // wave-local b128 coalesced stores (same-wave LDS ordering via lgkmcnt)
#pragma unroll
      for (int it = 0; it < 32 / RPS; ++it) {
        const int r2 = r2b + it * RPS;
        const u16x8 vv = *(const u16x8*)&eb[r2 * 72 + c2 * 8];
        *(u16x8*)&Cg[(size_t)(m0 + wm + hp * 32 + r2) * N + n0 + wn + c2 * 8] = vv;
      }
    }
  } else {
#pragma unroll
    for (int j = 0; j < FN; ++j) {
      const int col = n0 + wn + j * 16 + fr;
      const float bval = (EPI >= 1) ? bias[col] : 0.0f;
#pragma unroll
      for (int i = 0; i < MI; ++i) {
#pragma unroll
        for (int r = 0; r < 4; ++r) {
          const int row = m0 + wm + i * 16 + ((lane >> 4) << 2) + r;
          float v = acc[i][j][r] + bval;
          if (EPI == 3) v += resid[(size_t)row * N + col];
          ((float*)Cout)[(size_t)row * N + col] = v;
        }
      }
    }
  }
}

// ---------------- causal flash attention (R10 structure + T13 defer-max) ----------------
__global__ __launch_bounds__(512) void attn_k(
    const unsigned short* __restrict__ QKV, const unsigned short* __restrict__ VT,
    unsigned short* __restrict__ ctx) {
  __shared__ unsigned short Ks[2][64 * 64];
  __shared__ unsigned short Vs[2][64 * 64];
  __shared__ unsigned short Ps[8][16 * 64];
  int bxi = blockIdx.x, byi = blockIdx.y;
  xcd_swz(bxi, byi, 16, 32);
  const int qi = ((byi >> 1) & 1) ? (15 - bxi) : bxi;
  const int bh = byi, b = bh >> 4, h = bh & 15;
  const int nt = 2 * qi + 2;
  const int q0b = qi * 128;
  const int t = threadIdx.x, lane = t & 63, w = t >> 6;
  const int g = lane >> 4, c = lane & 15;
  const int cks = c & 7;
  const size_t base = (size_t)b * 2048 * 3072;

  const int r0 = t >> 3, ch0 = t & 7;
  const int lw = r0 * 64 + ((ch0 ^ (r0 & 7)) * 8);
  const unsigned short* Kg = QKV + base + 1024 + h * 64 + (size_t)r0 * 3072 + ch0 * 8;
  const unsigned short* Vg = VT + ((size_t)bh * 64 + r0) * 2048 + ch0 * 8;

  const int kro0 = (g ^ cks) * 8, kro1 = ((4 + g) ^ cks) * 8;

  bf16x8 onef;
#pragma unroll
  for (int i = 0; i < 8; ++i) onef[i] = (__bf16)1.0f;

  const int qrow = q0b + w * 16 + c;
  const unsigned short* qp = QKV + base + (size_t)qrow * 3072 + h * 64 + g * 8;
  const bf16x8 qf0 = *(const bf16x8*)qp;
  const bf16x8 qf1 = *(const bf16x8*)(qp + 32);

  f32x4 o[4];
#pragma unroll
  for (int d = 0; d < 4; ++d) o[d] = (f32x4){0.f, 0.f, 0.f, 0.f};
  f32x4 ol = (f32x4){0.f, 0.f, 0.f, 0.f};
  float mrow = -1e30f;

  u16x8 kr, vr;
#define ATTN_LOAD(kt_)                                        \
  {                                                           \
    kr = *(const u16x8*)(Kg + (size_t)(kt_) * 64 * 3072);     \
    vr = *(const u16x8*)(Vg + (kt_) * 64);                    \
  }
#define ATTN_WRITE(buf)                                       \
  {                                                           \
    *(u16x8*)&Ks[buf][lw] = kr;                               \
    *(u16x8*)&Vs[buf][lw] = vr;                               \
  }

  ATTN_LOAD(0);
  ATTN_WRITE(0);
  if (nt > 1) ATTN_LOAD(1);
  __syncthreads();

  const int fsrc = g * 20;

  for (int j = 0; j < nt; ++j) {
    const int cur = j & 1;
    const int kbase = j * 64;
    const bool active = (kbase <= q0b + w * 16 + 15);

    if (active) {
      f32x4 s4[4];
      __builtin_amdgcn_s_setprio(1);
#pragma unroll
      for (int t16 = 0; t16 < 4; ++t16) {
        const int krow = (t16 * 16 + c) * 64;
        const bf16x8 kf0 = *(const bf16x8*)&Ks[cur][krow + kro0];
        const bf16x8 kf1 = *(const bf16x8*)&Ks[cur][krow + kro1];
        f32x4 a = (f32x4){0.f, 0.f, 0.f, 0.f};
        a = mfma16(kf0, qf0, a);
        a = mfma16(kf1, qf1, a);
        s4[t16] = a;
      }
      __builtin_amdgcn_s_setprio(0);
      if (kbase + 63 > qrow) {
#pragma unroll
        for (int t16 = 0; t16 < 4; ++t16)
#pragma unroll
          for (int r = 0; r < 4; ++r)
            if (kbase + t16 * 16 + 4 * g + r > qrow) s4[t16][r] = -1e30f;
      }
      float mx = s4[0][0];
#pragma unroll
      for (int t16 = 0; t16 < 4; ++t16)
#pragma unroll
        for (int r = 0; r < 4; ++r) mx = fmaxf(mx, s4[t16][r]);
      mx = fmaxf(mx, __shfl_xor(mx, 16));
      mx = fmaxf(mx, __shfl_xor(mx, 32));
      if (!__all(mx <= mrow + 8.0f)) {
        const float mn = fmaxf(mrow, mx);
        const float fac = exp2f(mrow - mn);
        mrow = mn;
        float fo[4];
#pragma unroll
        for (int r = 0; r < 4; ++r) fo[r] = __shfl(fac, fsrc + r);
#pragma unroll
        for (int d = 0; d < 4; ++d)
#pragma unroll
          for (int r = 0; r < 4; ++r) o[d][r] *= fo[r];
#pragma unroll
        for (int r = 0; r < 4; ++r) ol[r] *= fo[r];
      }
#pragma unroll
      for (int t16 = 0; t16 < 4; ++t16) {
        bf16x4 pw;
#pragma unroll
        for (int r = 0; r < 4; ++r) pw[r] = (__bf16)exp2f(s4[t16][r] - mrow);
        *(bf16x4*)&Ps[w][c * 64 + (((2 * t16 + (g >> 1)) ^ cks) * 8) + (g & 1) * 4] = pw;
      }
      __builtin_amdgcn_s_setprio(1);
#pragma unroll
      for (int ks = 0; ks < 2; ++ks) {
        const int po = ((ks * 4 + g) ^ cks) * 8;
        const bf16x8 pf = *(const bf16x8*)&Ps[w][c * 64 + po];
#pragma unroll
        for (int d = 0; d < 4; ++d) {
          const bf16x8 vf = *(const bf16x8*)&Vs[cur][(d * 16 + c) * 64 + po];
          o[d] = mfma16(pf, vf, o[d]);
        }
        ol = mfma16(pf, onef, ol);
      }
      __builtin_amdgcn_s_setprio(0);
    }

    if (j + 1 < nt) {
      __syncthreads();
      ATTN_WRITE(cur ^ 1);
      if (j + 2 < nt) ATTN_LOAD(j + 2);
      __syncthreads();
    }
  }
#pragma unroll
  for (int d = 0; d < 4; ++d)
#pragma unroll
    for (int r = 0; r < 4; ++r) {
      const float v = o[d][r] / ol[r];
      ctx[(size_t)(b * 2048 + q0b + w * 16 + g * 4 + r) * 1024 + h * 64 + d * 16 + c] = f2bf(v);
    }
#undef ATTN_LOAD
#undef ATTN_WRITE
}

// ---------------- launch ----------------

extern "C" void kernel_launch(void* const* d_in, const int* in_sizes, int n_in,
                              void* d_out, int out_size, void* d_ws, size_t ws_size,
                              hipStream_t stream) {
  const float* hidden = (const float*)d_in[0];
  const float* ln1g = (const float*)d_in[1];
  const float* ln1b = (const float*)d_in[2];
  const float* ln2g = (const float*)d_in[3];
  const float* ln2b = (const float*)d_in[4];
  const float* qU = (const float*)d_in[5];
  const float* qV = (const float*)d_in[6];
  const float* qb = (const float*)d_in[7];
  const float* kU = (const float*)d_in[8];
  const float* kV = (const float*)d_in[9];
  const float* kb = (const float*)d_in[10];
  const float* vU = (const float*)d_in[11];
  const float* vV = (const float*)d_in[12];
  const float* vb = (const float*)d_in[13];
  const float* outU = (const float*)d_in[14];
  const float* outV = (const float*)d_in[15];
  const float* outb = (const float*)d_in[16];
  const float* fc1U = (const float*)d_in[17];
  const float* fc1V = (const float*)d_in[18];
  const float* fc1b = (const float*)d_in[19];
  const float* fc2U = (const float*)d_in[20];
  const float* fc2V = (const float*)d_in[21];
  const float* fc2b = (const float*)d_in[22];
  float* out = (float*)d_out;

  // workspace carve, lifetime-based aliasing
  char* p = (char*)d_ws;
  unsigned short* x1x2 = (unsigned short*)p; p += (size_t)4096 * 1024 * 2;   // x1 (LN1), later x2 (LN2)
  unsigned short* WqT_t1 = (unsigned short*)p; p += (size_t)3072 * 1024 * 2; // Wqkv^T, later t1
  float* bqkv = (float*)p; p += 3072 * 4;
  char* bigA = p; p += (size_t)4096 * 3072 * 2 + (size_t)4096 * 1024 * 2;    // QKV + ctx, later hmid
  unsigned short* QKV = (unsigned short*)bigA;
  unsigned short* ctxb = (unsigned short*)(bigA + (size_t)4096 * 3072 * 2);
  unsigned short* hmid = (unsigned short*)bigA;
  char* wo = p; p += (size_t)1024 * 768 * 2 * 2 + (size_t)1024 * 1024 * 2;   // outU,outV^T,Wout^T, later t2
  unsigned short* outUb = (unsigned short*)wo;
  unsigned short* outVT = (unsigned short*)(wo + (size_t)1024 * 768 * 2);
  unsigned short* WoutT = (unsigned short*)(wo + (size_t)1024 * 768 * 2 * 2);
  unsigned short* t2 = (unsigned short*)wo;
  float* hbuf = (float*)p; p += (size_t)4096 * 1024 * 4;                     // h (fp32 residual); VT aliases pre-attn
  unsigned short* VT = (unsigned short*)hbuf;                                // [32][64][2048] bf16 = 8MB
  unsigned short* fc1UT = (unsigned short*)p; p += (size_t)512 * 1024 * 2;
  unsigned short* fc1VT = (unsigned short*)p; p += (size_t)4096 * 512 * 2;
  unsigned short* fc2UT = (unsigned short*)p; p += (size_t)512 * 4096 * 2;
  unsigned short* fc2VT = (unsigned short*)p; p += (size_t)1024 * 512 * 2;

  const dim3 b256(256);
  const dim3 tb(32, 8);

  // weight prep
  concat_bias_k<<<12, b256, 0, stream>>>(qb, kb, vb, bqkv);
  wqkv_pre_k<<<dim3(16, 48), b256, 0, stream>>>(qU, qV, kU, kV, vU, vV, WqT_t1);
  tcvt_k<<<dim3(32, 24), tb, 0, stream>>>(outV, outVT, 768, 1024);
  cvt_k<<<768, b256, 0, stream>>>(outU, outUb, 1024 * 768);
  tcvt_k<<<dim3(16, 32), tb, 0, stream>>>(fc1U, fc1UT, 1024, 512);
  tcvt_k<<<dim3(128, 16), tb, 0, stream>>>(fc1V, fc1VT, 512, 4096);
  tcvt_k<<<dim3(16, 128), tb, 0, stream>>>(fc2U, fc2UT, 4096, 512);
  tcvt_k<<<dim3(32, 16), tb, 0, stream>>>(fc2V, fc2VT, 512, 1024);

  // attention path
  ln_k<<<4096, b256, 0, stream>>>(hidden, ln1g, ln1b, x1x2);
  gemm_k<128, 64, 1, 1><<<dim3(48, 32), b256, 0, stream>>>(x1x2, WqT_t1, bqkv, nullptr, QKV, 4096, 3072, 1024);
  vtr_k<<<dim3(64, 2, 32), tb, 0, stream>>>(QKV, VT);
  gemm_k<128, 128, 0, 1><<<dim3(8, 8), b256, 0, stream>>>(outVT, outUb, nullptr, nullptr, WoutT, 1024, 1024, 768);
  attn_k<<<dim3(16, 32), dim3(512), 0, stream>>>(QKV, VT, ctxb);
  gemm_k<64, 64, 3, 0><<<dim3(16, 64), b256, 0, stream>>>(ctxb, WoutT, outb, hidden, hbuf, 4096, 1024, 1024);

  // MLP path
  ln_k<<<4096, b256, 0, stream>>>(hbuf, ln2g, ln2b, x1x2);
  gemm_k<64, 64, 0, 1><<<dim3(8, 64), b256, 0, stream>>>(x1x2, fc1UT, nullptr, nullptr, WqT_t1, 4096, 512, 1024);
  gemm_k<128, 64, 2, 1><<<dim3(64, 32), b256, 0, stream>>>(WqT_t1, fc1VT, fc1b, nullptr, hmid, 4096, 4096, 512);
  gemm_k<64, 64, 0, 1><<<dim3(8, 64), b256, 0, stream>>>(hmid, fc2UT, nullptr, nullptr, t2, 4096, 512, 4096);
  gemm_k<64, 64, 3, 0><<<dim3(16, 64), b256, 0, stream>>>(t2, fc2VT, fc2b, hbuf, out, 4096, 1024, 512);
}

// Round 15
// 253.321 us; speedup vs baseline: 1.1382x; 1.1382x over previous
//
#include <hip/hip_runtime.h>
#include <hip/hip_bf16.h>

typedef float f32x4 __attribute__((ext_vector_type(4)));
typedef __bf16 bf16x8 __attribute__((ext_vector_type(8)));
typedef __bf16 bf16x4 __attribute__((ext_vector_type(4)));
typedef unsigned short u16x8 __attribute__((ext_vector_type(8)));
typedef unsigned short u16x4 __attribute__((ext_vector_type(4)));

#define QSCALE 0.180336881f  /* 0.125 * log2(e): folds attn scale + exp2 domain into Q */

__device__ __forceinline__ unsigned short f2bf(float f) {
  union { float f; unsigned int u; } v; v.f = f;
  return (unsigned short)((v.u + 0x7FFFu + ((v.u >> 16) & 1u)) >> 16);
}

__device__ __forceinline__ f32x4 mfma16(bf16x8 a, bf16x8 b, f32x4 c) {
  return __builtin_amdgcn_mfma_f32_16x16x32_bf16(a, b, c, 0, 0, 0);
}

__device__ __forceinline__ void gload16(const unsigned short* g, unsigned short* l) {
  __builtin_amdgcn_global_load_lds(
      (const __attribute__((address_space(1))) void*)g,
      (__attribute__((address_space(3))) void*)l, 16, 0, 0);
}

// ---------------- small utility kernels ----------------

__global__ void concat_bias_k(const float* __restrict__ qb, const float* __restrict__ kb,
                              const float* __restrict__ vb, float* __restrict__ out) {
  const int i = blockIdx.x * 256 + threadIdx.x;
  if (i >= 3072) return;
  const float* s = (i < 1024) ? qb : (i < 2048 ? kb : vb);
  out[i] = s[i & 1023] * (i < 1024 ? QSCALE : 1.0f);
}

// fp32 [R,C] -> bf16 [C,R]
__global__ void tcvt_k(const float* __restrict__ in, unsigned short* __restrict__ out,
                       int R, int C) {
  __shared__ float tile[32][33];
  const int x = blockIdx.x * 32 + threadIdx.x;
  const int y0 = blockIdx.y * 32;
#pragma unroll
  for (int i = 0; i < 32; i += 8)
    tile[threadIdx.y + i][threadIdx.x] = in[(size_t)(y0 + threadIdx.y + i) * C + x];
  __syncthreads();
  const int ox = y0 + threadIdx.x;
  const int oy0 = blockIdx.x * 32;
#pragma unroll
  for (int i = 0; i < 32; i += 8)
    out[(size_t)(oy0 + threadIdx.y + i) * R + ox] = f2bf(tile[threadIdx.x][threadIdx.y + i]);
}

__global__ void cvt_k(const float* __restrict__ in, unsigned short* __restrict__ out, int n) {
  const int i = (blockIdx.x * 256 + threadIdx.x) * 4;
  if (i >= n) return;
  const f32x4 v = *(const f32x4*)(in + i);
  u16x4 o;
#pragma unroll
  for (int k = 0; k < 4; ++k) o[k] = f2bf(v[k]);
  *(u16x4*)(out + i) = o;
}

// V-transpose: QKV[b][s][2048 + h*64 + d] -> VT[(b*16+h)][d][s]  (bf16)
__global__ void vtr_k(const unsigned short* __restrict__ QKV, unsigned short* __restrict__ VT) {
  __shared__ unsigned short tile[32][33];
  const int bh = blockIdx.z, b = bh >> 4, h = bh & 15;
  const int s0 = blockIdx.x * 32, d0 = blockIdx.y * 32;
  const unsigned short* src = QKV + (size_t)b * 2048 * 3072 + 2048 + h * 64;
#pragma unroll
  for (int i = 0; i < 32; i += 8)
    tile[threadIdx.y + i][threadIdx.x] = src[(size_t)(s0 + threadIdx.y + i) * 3072 + d0 + threadIdx.x];
  __syncthreads();
  unsigned short* dst = VT + (size_t)bh * 64 * 2048;
#pragma unroll
  for (int i = 0; i < 32; i += 8)
    dst[(size_t)(d0 + threadIdx.y + i) * 2048 + s0 + threadIdx.x] = tile[threadIdx.x][threadIdx.y + i];
}

// Wqkv^T[(m*1024 + h*64 + e)*1024 + d] = sum_r U_m[d,h,r] * V_m[h,r,e]  (Q part scaled)
__global__ __launch_bounds__(256) void wqkv_pre_k(
    const float* __restrict__ qU, const float* __restrict__ qV,
    const float* __restrict__ kU, const float* __restrict__ kV,
    const float* __restrict__ vU, const float* __restrict__ vV,
    unsigned short* __restrict__ WT) {
  __shared__ float Us[64][48];
  __shared__ float Vs[48][64];
  const int m = blockIdx.y >> 4, h = blockIdx.y & 15;
  const int d0 = blockIdx.x * 64;
  const float* U = (m == 0) ? qU : (m == 1 ? kU : vU);
  const float* V = (m == 0) ? qV : (m == 1 ? kV : vV);
  const float qs = (m == 0) ? QSCALE : 1.0f;
  const int t = threadIdx.x;
  for (int idx = t; idx < 64 * 48; idx += 256) {
    const int d = idx / 48, r = idx - d * 48;
    Us[d][r] = U[(size_t)(d0 + d) * 768 + h * 48 + r];
  }
  for (int idx = t; idx < 48 * 64; idx += 256) {
    const int r = idx >> 6, e = idx & 63;
    Vs[r][e] = V[(h * 48 + r) * 64 + e];
  }
  __syncthreads();
  const int e = t & 63, dg = t >> 6;
  for (int j = 0; j < 16; ++j) {
    const int d = dg * 16 + j;
    float s = 0.f;
#pragma unroll
    for (int r = 0; r < 48; ++r) s = fmaf(Us[d][r], Vs[r][e], s);
    WT[(size_t)(m * 1024 + h * 64 + e) * 1024 + d0 + d] = f2bf(s * qs);
  }
}

// LayerNorm over D=1024, fp32 in, bf16 out. One block per row.
__global__ __launch_bounds__(256) void ln_k(
    const float* __restrict__ in, const float* __restrict__ gw,
    const float* __restrict__ bw, unsigned short* __restrict__ out) {
  const int row = blockIdx.x, t = threadIdx.x;
  const f32x4 v = *(const f32x4*)(in + (size_t)row * 1024 + t * 4);
  float s = v[0] + v[1] + v[2] + v[3];
  float ss = v[0] * v[0] + v[1] * v[1] + v[2] * v[2] + v[3] * v[3];
#pragma unroll
  for (int off = 1; off < 64; off <<= 1) {
    s += __shfl_xor(s, off);
    ss += __shfl_xor(ss, off);
  }
  __shared__ float red[8];
  if ((t & 63) == 0) { red[(t >> 6) * 2] = s; red[(t >> 6) * 2 + 1] = ss; }
  __syncthreads();
  s = red[0] + red[2] + red[4] + red[6];
  ss = red[1] + red[3] + red[5] + red[7];
  const float mean = s * (1.0f / 1024.0f);
  const float rstd = rsqrtf(ss * (1.0f / 1024.0f) - mean * mean + 1e-5f);
  const f32x4 g4 = *(const f32x4*)(gw + t * 4);
  const f32x4 b4 = *(const f32x4*)(bw + t * 4);
  u16x4 o;
#pragma unroll
  for (int i = 0; i < 4; ++i) o[i] = f2bf((v[i] - mean) * rstd * g4[i] + b4[i]);
  *(u16x4*)(out + (size_t)row * 1024 + t * 4) = o;
}

// bijective XCD chunking (m157/m204)
__device__ __forceinline__ void xcd_swz(int& bx, int& by, int nx, int ny) {
  const int nwg = nx * ny;
  if ((nwg & 7) == 0) {
    const int d = by * nx + bx;
    const int k = (d & 7) * (nwg >> 3) + (d >> 3);
    bx = k % nx;
    by = k / nx;
  }
}

#define WVM(N) asm volatile("s_waitcnt vmcnt(%0)" ::"n"(N) : "memory")

// ---------------- 128x128 8-wave GEMM (occupancy-doubled, R10 schedule) ----------------
// Same 128^2 tile / BK=32 / 3-buffer counted-vmcnt schedule as the R10 best,
// but 512 threads = 8 waves (2M x 4N, wave tile 64x32): 2x the resident waves
// per CU at identical FETCH/reuse -> tests the waves/SIMD latency-hiding
// theory in isolation. bf16 out, EPI 1=+bias, 2=+bias+gelu.
template <int EPI>
__global__ __launch_bounds__(512) void gemm8_k(
    const unsigned short* __restrict__ A, const unsigned short* __restrict__ Bt,
    const float* __restrict__ bias, unsigned short* __restrict__ Cout,
    int M, int N, int K) {
  constexpr int ASZ = 128 * 32;
  __shared__ unsigned short smem[6 * ASZ];  // A[3][ASZ] + B[3][ASZ] = 48 KB
  unsigned short* As = smem;
  unsigned short* Bs = smem + 3 * ASZ;
  int bxi = blockIdx.x, byi = blockIdx.y;
  xcd_swz(bxi, byi, gridDim.x, gridDim.y);
  const int t = threadIdx.x;
  const int lane = t & 63, wid = t >> 6;
  const int m0 = byi * 128, n0 = bxi * 128;
  const int wm = (wid & 1) * 64, wn = (wid >> 1) * 32;
  const int fr = lane & 15, fg = (lane >> 4) * 8;

  f32x4 acc[4][2];
#pragma unroll
  for (int i = 0; i < 4; ++i)
#pragma unroll
    for (int j = 0; j < 2; ++j) acc[i][j] = (f32x4){0.f, 0.f, 0.f, 0.f};

  // staging: 512 threads cover one 128x32 part each for A and B (1 gload each)
  const unsigned short* Ag = A + (size_t)(m0 + (t >> 2)) * K + (t & 3) * 8;
  const unsigned short* Bg = Bt + (size_t)(n0 + (t >> 2)) * K + (t & 3) * 8;
  const int l0 = t * 8;

#define STG8(buf, ke)                          \
  {                                            \
    gload16(Ag + (ke), &As[(buf) * ASZ + l0]); \
    gload16(Bg + (ke), &Bs[(buf) * ASZ + l0]); \
  }

  const int nk = K >> 5;  // >= 3 for all uses (16, 32)
  STG8(0, 0)
  STG8(1, 32)

  int cur = 0, sb = 2;
  for (int kt = 0; kt < nk; ++kt) {
    if (kt + 1 < nk) WVM(2); else WVM(0);
    __builtin_amdgcn_s_barrier();
    __builtin_amdgcn_sched_barrier(0);
    if (kt + 2 < nk) STG8(sb, (kt + 2) * 32);
    bf16x8 af[4], bf[2];
#pragma unroll
    for (int i = 0; i < 4; ++i)
      af[i] = *(const bf16x8*)&As[cur * ASZ + (wm + i * 16 + fr) * 32 + fg];
#pragma unroll
    for (int j = 0; j < 2; ++j)
      bf[j] = *(const bf16x8*)&Bs[cur * ASZ + (wn + j * 16 + fr) * 32 + fg];
#pragma unroll
    for (int i = 0; i < 4; ++i)
#pragma unroll
      for (int j = 0; j < 2; ++j) acc[i][j] = mfma16(af[i], bf[j], acc[i][j]);
    cur = (cur == 2) ? 0 : cur + 1;
    sb = (sb == 2) ? 0 : sb + 1;
  }
#undef STG8

  // epilogue: wave-private [64][40] bounce -> coalesced b128 stores
  __syncthreads();
  unsigned short* eb = smem + wid * (64 * 40);  // 8 x 5120 = 40960 elems <= 48K
#pragma unroll
  for (int j = 0; j < 2; ++j) {
    const int colL = j * 16 + fr;
    const float bval = bias[n0 + wn + colL];
#pragma unroll
    for (int i = 0; i < 4; ++i) {
#pragma unroll
      for (int r = 0; r < 4; ++r) {
        const int rl = i * 16 + ((lane >> 4) << 2) + r;
        float v = acc[i][j][r] + bval;
        if (EPI == 2) {  // gelu tanh-approx
          const float z = 0.7978845608028654f * (v + 0.044715f * v * v * v);
          v = v - v / (__expf(2.0f * z) + 1.0f);
        }
        eb[rl * 40 + colL] = f2bf(v);
      }
    }
  }
  const int c2 = lane & 3, r2b = lane >> 2;
#pragma unroll
  for (int it = 0; it < 4; ++it) {
    const int r2 = r2b + it * 16;
    const u16x8 vv = *(const u16x8*)&eb[r2 * 40 + c2 * 8];
    *(u16x8*)&Cout[(size_t)(m0 + wm + r2) * N + n0 + wn + c2 * 8] = vv;
  }
}

// ---------------- generic bf16 MFMA GEMM (R10 3-buffer counted, narrow shapes) ----------------
template <int BM, int BN, int EPI, int OUTBF>
__global__ __launch_bounds__(256) void gemm_k(
    const unsigned short* __restrict__ A, const unsigned short* __restrict__ Bt,
    const float* __restrict__ bias, const float* __restrict__ resid,
    void* __restrict__ Cout, int M, int N, int K) {
  constexpr int MI = BM / 32;
  constexpr int FN = BN / 32;
  constexpr int NL = (BM == 128 ? 2 : 1) + (BN == 128 ? 2 : 1);
  constexpr int ASZ = BM * 32, BSZ = BN * 32;
  constexpr int SM_KLOOP = 3 * (ASZ + BSZ);
  constexpr int SM_EPI = OUTBF ? 4 * (BM / 2) * 72 : 0;
  constexpr int SME = SM_KLOOP > SM_EPI ? SM_KLOOP : SM_EPI;
  __shared__ unsigned short smem[SME];
  unsigned short* As = smem;
  unsigned short* Bs = smem + 3 * ASZ;
  int bxi = blockIdx.x, byi = blockIdx.y;
  xcd_swz(bxi, byi, gridDim.x, gridDim.y);
  const int t = threadIdx.x;
  const int lane = t & 63, wid = t >> 6;
  const int m0 = byi * BM, n0 = bxi * BN;
  const int wm = (wid >> 1) * (BM / 2), wn = (wid & 1) * (BN / 2);
  const int fr = lane & 15, fg = (lane >> 4) * 8;

  f32x4 acc[MI][FN];
#pragma unroll
  for (int i = 0; i < MI; ++i)
#pragma unroll
    for (int j = 0; j < FN; ++j) acc[i][j] = (f32x4){0.f, 0.f, 0.f, 0.f};

  const unsigned short* Ag0 = A + (size_t)(m0 + (t >> 2)) * K + (t & 3) * 8;
  const unsigned short* Ag1 = A + (size_t)(m0 + 64 + (t >> 2)) * K + (t & 3) * 8;
  const unsigned short* Bg0 = Bt + (size_t)(n0 + (t >> 2)) * K + (t & 3) * 8;
  const unsigned short* Bg1 = Bt + (size_t)(n0 + 64 + (t >> 2)) * K + (t & 3) * 8;
  const int l0 = t * 8;

#define GEMM_STAGE(buf, ke)                                               \
  {                                                                       \
    gload16(Ag0 + (ke), &As[(buf) * ASZ + l0]);                           \
    if (BM == 128) gload16(Ag1 + (ke), &As[(buf) * ASZ + l0 + 2048]);     \
    gload16(Bg0 + (ke), &Bs[(buf) * BSZ + l0]);                           \
    if (BN == 128) gload16(Bg1 + (ke), &Bs[(buf) * BSZ + l0 + 2048]);     \
  }

  const int nk = K >> 5;
  GEMM_STAGE(0, 0);
  if (nk > 1) GEMM_STAGE(1, 32);

  int cur = 0, sb = 2;
  for (int kt = 0; kt < nk; ++kt) {
    if (kt + 1 < nk)
      WVM(NL);
    else
      WVM(0);
    __builtin_amdgcn_s_barrier();
    __builtin_amdgcn_sched_barrier(0);
    if (kt + 2 < nk) GEMM_STAGE(sb, (kt + 2) * 32);
    bf16x8 af[MI], bfr[FN];
#pragma unroll
    for (int i = 0; i < MI; ++i)
      af[i] = *(const bf16x8*)&As[cur * ASZ + (wm + i * 16 + fr) * 32 + fg];
#pragma unroll
    for (int j = 0; j < FN; ++j)
      bfr[j] = *(const bf16x8*)&Bs[cur * BSZ + (wn + j * 16 + fr) * 32 + fg];
#pragma unroll
    for (int i = 0; i < MI; ++i)
#pragma unroll
      for (int j = 0; j < FN; ++j) acc[i][j] = mfma16(af[i], bfr[j], acc[i][j]);
    cur = (cur == 2) ? 0 : cur + 1;
    sb = (sb == 2) ? 0 : sb + 1;
  }
#undef GEMM_STAGE

  if (OUTBF) {
    __syncthreads();
    unsigned short* eb = smem + wid * ((BM / 2) * 72);
#pragma unroll
    for (int j = 0; j < FN; ++j) {
      const int colL = j * 16 + fr;
      const float bval = (EPI >= 1) ? bias[n0 + wn + colL] : 0.0f;
#pragma unroll
      for (int i = 0; i < MI; ++i) {
#pragma unroll
        for (int r = 0; r < 4; ++r) {
          const int rl = i * 16 + ((lane >> 4) << 2) + r;
          float v = acc[i][j][r] + bval;
          if (EPI == 2) {
            const float z = 0.7978845608028654f * (v + 0.044715f * v * v * v);
            v = v - v / (__expf(2.0f * z) + 1.0f);
          }
          eb[rl * 72 + colL] = f2bf(v);
        }
      }
    }
    __builtin_amdgcn_s_barrier();
    constexpr int CH = (BN / 2) / 8;
    constexpr int RPI = 64 / CH;
    const int c2 = lane % CH, r2b = lane / CH;
    unsigned short* Cg = (unsigned short*)Cout;
#pragma unroll
    for (int it = 0; it < (BM / 2) / RPI; ++it) {
      const int r2 = r2b + it * RPI;
      const u16x8 vv = *(const u16x8*)&eb[r2 * 72 + c2 * 8];
      *(u16x8*)&Cg[(size_t)(m0 + wm + r2) * N + n0 + wn + c2 * 8] = vv;
    }
  } else {
#pragma unroll
    for (int j = 0; j < FN; ++j) {
      const int col = n0 + wn + j * 16 + fr;
      const float bval = (EPI >= 1) ? bias[col] : 0.0f;
#pragma unroll
      for (int i = 0; i < MI; ++i) {
#pragma unroll
        for (int r = 0; r < 4; ++r) {
          const int row = m0 + wm + i * 16 + ((lane >> 4) << 2) + r;
          float v = acc[i][j][r] + bval;
          if (EPI == 3) v += resid[(size_t)row * N + col];
          ((float*)Cout)[(size_t)row * N + col] = v;
        }
      }
    }
  }
}

// ---------------- causal flash attention (R10 structure + T13 defer-max) ----------------
__global__ __launch_bounds__(512) void attn_k(
    const unsigned short* __restrict__ QKV, const unsigned short* __restrict__ VT,
    unsigned short* __restrict__ ctx) {
  __shared__ unsigned short Ks[2][64 * 64];
  __shared__ unsigned short Vs[2][64 * 64];
  __shared__ unsigned short Ps[8][16 * 64];
  int bxi = blockIdx.x, byi = blockIdx.y;
  xcd_swz(bxi, byi, 16, 32);
  const int qi = ((byi >> 1) & 1) ? (15 - bxi) : bxi;
  const int bh = byi, b = bh >> 4, h = bh & 15;
  const int nt = 2 * qi + 2;
  const int q0b = qi * 128;
  const int t = threadIdx.x, lane = t & 63, w = t >> 6;
  const int g = lane >> 4, c = lane & 15;
  const int cks = c & 7;
  const size_t base = (size_t)b * 2048 * 3072;

  const int r0 = t >> 3, ch0 = t & 7;
  const int lw = r0 * 64 + ((ch0 ^ (r0 & 7)) * 8);
  const unsigned short* Kg = QKV + base + 1024 + h * 64 + (size_t)r0 * 3072 + ch0 * 8;
  const unsigned short* Vg = VT + ((size_t)bh * 64 + r0) * 2048 + ch0 * 8;

  const int kro0 = (g ^ cks) * 8, kro1 = ((4 + g) ^ cks) * 8;

  bf16x8 onef;
#pragma unroll
  for (int i = 0; i < 8; ++i) onef[i] = (__bf16)1.0f;

  const int qrow = q0b + w * 16 + c;
  const unsigned short* qp = QKV + base + (size_t)qrow * 3072 + h * 64 + g * 8;
  const bf16x8 qf0 = *(const bf16x8*)qp;
  const bf16x8 qf1 = *(const bf16x8*)(qp + 32);

  f32x4 o[4];
#pragma unroll
  for (int d = 0; d < 4; ++d) o[d] = (f32x4){0.f, 0.f, 0.f, 0.f};
  f32x4 ol = (f32x4){0.f, 0.f, 0.f, 0.f};
  float mrow = -1e30f;

  u16x8 kr, vr;
#define ATTN_LOAD(kt_)                                        \
  {                                                           \
    kr = *(const u16x8*)(Kg + (size_t)(kt_) * 64 * 3072);     \
    vr = *(const u16x8*)(Vg + (kt_) * 64);                    \
  }
#define ATTN_WRITE(buf)                                       \
  {                                                           \
    *(u16x8*)&Ks[buf][lw] = kr;                               \
    *(u16x8*)&Vs[buf][lw] = vr;                               \
  }

  ATTN_LOAD(0);
  ATTN_WRITE(0);
  if (nt > 1) ATTN_LOAD(1);
  __syncthreads();

  const int fsrc = g * 20;

  for (int j = 0; j < nt; ++j) {
    const int cur = j & 1;
    const int kbase = j * 64;
    const bool active = (kbase <= q0b + w * 16 + 15);

    if (active) {
      f32x4 s4[4];
      __builtin_amdgcn_s_setprio(1);
#pragma unroll
      for (int t16 = 0; t16 < 4; ++t16) {
        const int krow = (t16 * 16 + c) * 64;
        const bf16x8 kf0 = *(const bf16x8*)&Ks[cur][krow + kro0];
        const bf16x8 kf1 = *(const bf16x8*)&Ks[cur][krow + kro1];
        f32x4 a = (f32x4){0.f, 0.f, 0.f, 0.f};
        a = mfma16(kf0, qf0, a);
        a = mfma16(kf1, qf1, a);
        s4[t16] = a;
      }
      __builtin_amdgcn_s_setprio(0);
      if (kbase + 63 > qrow) {
#pragma unroll
        for (int t16 = 0; t16 < 4; ++t16)
#pragma unroll
          for (int r = 0; r < 4; ++r)
            if (kbase + t16 * 16 + 4 * g + r > qrow) s4[t16][r] = -1e30f;
      }
      float mx = s4[0][0];
#pragma unroll
      for (int t16 = 0; t16 < 4; ++t16)
#pragma unroll
        for (int r = 0; r < 4; ++r) mx = fmaxf(mx, s4[t16][r]);
      mx = fmaxf(mx, __shfl_xor(mx, 16));
      mx = fmaxf(mx, __shfl_xor(mx, 32));
      if (!__all(mx <= mrow + 8.0f)) {
        const float mn = fmaxf(mrow, mx);
        const float fac = exp2f(mrow - mn);
        mrow = mn;
        float fo[4];
#pragma unroll
        for (int r = 0; r < 4; ++r) fo[r] = __shfl(fac, fsrc + r);
#pragma unroll
        for (int d = 0; d < 4; ++d)
#pragma unroll
          for (int r = 0; r < 4; ++r) o[d][r] *= fo[r];
#pragma unroll
        for (int r = 0; r < 4; ++r) ol[r] *= fo[r];
      }
#pragma unroll
      for (int t16 = 0; t16 < 4; ++t16) {
        bf16x4 pw;
#pragma unroll
        for (int r = 0; r < 4; ++r) pw[r] = (__bf16)exp2f(s4[t16][r] - mrow);
        *(bf16x4*)&Ps[w][c * 64 + (((2 * t16 + (g >> 1)) ^ cks) * 8) + (g & 1) * 4] = pw;
      }
      __builtin_amdgcn_s_setprio(1);
#pragma unroll
      for (int ks = 0; ks < 2; ++ks) {
        const int po = ((ks * 4 + g) ^ cks) * 8;
        const bf16x8 pf = *(const bf16x8*)&Ps[w][c * 64 + po];
#pragma unroll
        for (int d = 0; d < 4; ++d) {
          const bf16x8 vf = *(const bf16x8*)&Vs[cur][(d * 16 + c) * 64 + po];
          o[d] = mfma16(pf, vf, o[d]);
        }
        ol = mfma16(pf, onef, ol);
      }
      __builtin_amdgcn_s_setprio(0);
    }

    if (j + 1 < nt) {
      __syncthreads();
      ATTN_WRITE(cur ^ 1);
      if (j + 2 < nt) ATTN_LOAD(j + 2);
      __syncthreads();
    }
  }
#pragma unroll
  for (int d = 0; d < 4; ++d)
#pragma unroll
    for (int r = 0; r < 4; ++r) {
      const float v = o[d][r] / ol[r];
      ctx[(size_t)(b * 2048 + q0b + w * 16 + g * 4 + r) * 1024 + h * 64 + d * 16 + c] = f2bf(v);
    }
#undef ATTN_LOAD
#undef ATTN_WRITE
}

// ---------------- launch ----------------

extern "C" void kernel_launch(void* const* d_in, const int* in_sizes, int n_in,
                              void* d_out, int out_size, void* d_ws, size_t ws_size,
                              hipStream_t stream) {
  const float* hidden = (const float*)d_in[0];
  const float* ln1g = (const float*)d_in[1];
  const float* ln1b = (const float*)d_in[2];
  const float* ln2g = (const float*)d_in[3];
  const float* ln2b = (const float*)d_in[4];
  const float* qU = (const float*)d_in[5];
  const float* qV = (const float*)d_in[6];
  const float* qb = (const float*)d_in[7];
  const float* kU = (const float*)d_in[8];
  const float* kV = (const float*)d_in[9];
  const float* kb = (const float*)d_in[10];
  const float* vU = (const float*)d_in[11];
  const float* vV = (const float*)d_in[12];
  const float* vb = (const float*)d_in[13];
  const float* outU = (const float*)d_in[14];
  const float* outV = (const float*)d_in[15];
  const float* outb = (const float*)d_in[16];
  const float* fc1U = (const float*)d_in[17];
  const float* fc1V = (const float*)d_in[18];
  const float* fc1b = (const float*)d_in[19];
  const float* fc2U = (const float*)d_in[20];
  const float* fc2V = (const float*)d_in[21];
  const float* fc2b = (const float*)d_in[22];
  float* out = (float*)d_out;

  // workspace carve, lifetime-based aliasing
  char* p = (char*)d_ws;
  unsigned short* x1x2 = (unsigned short*)p; p += (size_t)4096 * 1024 * 2;   // x1 (LN1), later x2 (LN2)
  unsigned short* WqT_t1 = (unsigned short*)p; p += (size_t)3072 * 1024 * 2; // Wqkv^T, later t1
  float* bqkv = (float*)p; p += 3072 * 4;
  char* bigA = p; p += (size_t)4096 * 3072 * 2 + (size_t)4096 * 1024 * 2;    // QKV + ctx, later hmid
  unsigned short* QKV = (unsigned short*)bigA;
  unsigned short* ctxb = (unsigned short*)(bigA + (size_t)4096 * 3072 * 2);
  unsigned short* hmid = (unsigned short*)bigA;
  char* wo = p; p += (size_t)1024 * 768 * 2 * 2 + (size_t)1024 * 1024 * 2;   // outU,outV^T,Wout^T, later t2
  unsigned short* outUb = (unsigned short*)wo;
  unsigned short* outVT = (unsigned short*)(wo + (size_t)1024 * 768 * 2);
  unsigned short* WoutT = (unsigned short*)(wo + (size_t)1024 * 768 * 2 * 2);
  unsigned short* t2 = (unsigned short*)wo;
  float* hbuf = (float*)p; p += (size_t)4096 * 1024 * 4;                     // h (fp32 residual); VT aliases pre-attn
  unsigned short* VT = (unsigned short*)hbuf;                                // [32][64][2048] bf16 = 8MB
  unsigned short* fc1UT = (unsigned short*)p; p += (size_t)512 * 1024 * 2;
  unsigned short* fc1VT = (unsigned short*)p; p += (size_t)4096 * 512 * 2;
  unsigned short* fc2UT = (unsigned short*)p; p += (size_t)512 * 4096 * 2;
  unsigned short* fc2VT = (unsigned short*)p; p += (size_t)1024 * 512 * 2;

  const dim3 b256(256);
  const dim3 b512(512);
  const dim3 tb(32, 8);

  // weight prep
  concat_bias_k<<<12, b256, 0, stream>>>(qb, kb, vb, bqkv);
  wqkv_pre_k<<<dim3(16, 48), b256, 0, stream>>>(qU, qV, kU, kV, vU, vV, WqT_t1);
  tcvt_k<<<dim3(32, 24), tb, 0, stream>>>(outV, outVT, 768, 1024);
  cvt_k<<<768, b256, 0, stream>>>(outU, outUb, 1024 * 768);
  tcvt_k<<<dim3(16, 32), tb, 0, stream>>>(fc1U, fc1UT, 1024, 512);
  tcvt_k<<<dim3(128, 16), tb, 0, stream>>>(fc1V, fc1VT, 512, 4096);
  tcvt_k<<<dim3(16, 128), tb, 0, stream>>>(fc2U, fc2UT, 4096, 512);
  tcvt_k<<<dim3(32, 16), tb, 0, stream>>>(fc2V, fc2VT, 512, 1024);

  // attention path
  ln_k<<<4096, b256, 0, stream>>>(hidden, ln1g, ln1b, x1x2);
  gemm8_k<1><<<dim3(24, 32), b512, 0, stream>>>(x1x2, WqT_t1, bqkv, QKV, 4096, 3072, 1024);
  vtr_k<<<dim3(64, 2, 32), tb, 0, stream>>>(QKV, VT);
  gemm_k<128, 128, 0, 1><<<dim3(8, 8), b256, 0, stream>>>(outVT, outUb, nullptr, nullptr, WoutT, 1024, 1024, 768);
  attn_k<<<dim3(16, 32), b512, 0, stream>>>(QKV, VT, ctxb);
  gemm_k<64, 128, 3, 0><<<dim3(8, 64), b256, 0, stream>>>(ctxb, WoutT, outb, hidden, hbuf, 4096, 1024, 1024);

  // MLP path
  ln_k<<<4096, b256, 0, stream>>>(hbuf, ln2g, ln2b, x1x2);
  gemm_k<64, 64, 0, 1><<<dim3(8, 64), b256, 0, stream>>>(x1x2, fc1UT, nullptr, nullptr, WqT_t1, 4096, 512, 1024);
  gemm8_k<2><<<dim3(32, 32), b512, 0, stream>>>(WqT_t1, fc1VT, fc1b, hmid, 4096, 4096, 512);
  gemm_k<64, 64, 0, 1><<<dim3(8, 64), b256, 0, stream>>>(hmid, fc2UT, nullptr, nullptr, t2, 4096, 512, 4096);
  gemm_k<64, 128, 3, 0><<<dim3(8, 64), b256, 0, stream>>>(t2, fc2VT, fc2b, hbuf, out, 4096, 1024, 512);
}